// Round 12
// baseline (454.321 us; speedup 1.0000x reference)
//
#include <hip/hip_runtime.h>
#include <cfloat>
#include <math.h>

// Problem constants
#define N_TEXT  226
#define N_IMG   5400
#define N_TOKEN 5626
#define HEAD_STRIDE 31651876u   // N_TOKEN*N_TOKEN
#define HEAD_F4     7912969u    // HEAD_STRIDE/4
#define TOTAL_F4    31651876u   // 4 heads * HEAD_F4
#define NTILE 6966              // 27^2+36^2+45^2+54^2

// f32(1/15): XLA rewrites divide-by-constant into multiply-by-reciprocal.
#define RCP15 0x1.111112p-4f

typedef float f32x4 __attribute__((ext_vector_type(4)));
typedef float f32x2 __attribute__((ext_vector_type(2)));

// Locked bit-exact arithmetic (verified r9/r11, absmax=0):
//   scale = fl32(delta*fl32(1/15)); safe = scale==0?1:scale;
//   recip = fl32(1/safe); q = clip(roundeven(fl32(x*recip)),0,15);
//   out = fl32(q*scale).
__device__ __forceinline__ float fq1(float x, float recip, float scale) {
    float q = rintf(__fmul_rn(x, recip));
    q = fminf(fmaxf(q, 0.0f), 15.0f);
    return __fmul_rn(q, scale);
}

// ---------------------------------------------------------------------------
// K0: zero the delta LUT (ws is poisoned; must re-init every launch).
// ---------------------------------------------------------------------------
__global__ void k0_init(unsigned* __restrict__ delta_u) {
    const int t = blockIdx.x * 256 + threadIdx.x;
    if (t < NTILE) delta_u[t] = 0u;
}

// ---------------------------------------------------------------------------
// K1: one block per image row. Coalesced f4 row load -> LDS; each wave
// reduces tile-columns (stride-4) from LDS; lane0 atomicMax (float-as-uint,
// valid for non-negative values; exact max is order-independent).
// ---------------------------------------------------------------------------
template <int BW, int NB, int BASE>
__device__ __forceinline__ void row_max(const float* __restrict__ in,
                                        unsigned* __restrict__ delta_u,
                                        float* __restrict__ lds,
                                        int r, int head) {
    const unsigned base = (unsigned)head * HEAD_STRIDE
                        + (unsigned)(N_TEXT + r) * N_TOKEN + N_TEXT;
    const float* rp = in + base;
    const int tid = threadIdx.x;
    const int off  = (int)((0u - base) & 3u);        // 0 or 2
    const int nf4  = (N_IMG - off) >> 2;             // 1349 or 1350
    const int tail = N_IMG - off - (nf4 << 2);       // 0 or 2

    if (tid == 0 && off) {
        f32x2 v = *(const f32x2*)rp;
        lds[0] = v.x; lds[1] = v.y;
    }
    if (tid == 1 && tail) {
        const int p = off + (nf4 << 2);
        f32x2 v = *(const f32x2*)(rp + p);
        lds[p] = v.x; lds[p + 1] = v.y;
    }
    for (int i = tid; i < nf4; i += 256) {
        f32x4 v = *(const f32x4*)(rp + off + (i << 2));
        const int j = off + (i << 2);
        lds[j] = v.x; lds[j+1] = v.y; lds[j+2] = v.z; lds[j+3] = v.w;
    }
    __syncthreads();

    const int wid = tid >> 6, lane = tid & 63;
    const int bi  = r / BW;
    for (int bj = wid; bj < NB; bj += 4) {
        float m = 0.0f;                               // inputs are >= 0
        for (int k = lane; k < BW; k += 64)
            m = fmaxf(m, lds[bj * BW + k]);
        #pragma unroll
        for (int o = 32; o > 0; o >>= 1)
            m = fmaxf(m, __shfl_xor(m, o));
        if (lane == 0)
            atomicMax(&delta_u[BASE + bi * NB + bj], __float_as_uint(m));
    }
}

__global__ __launch_bounds__(256)
void k1_rowmax(const float* __restrict__ in, unsigned* __restrict__ delta_u) {
    __shared__ float lds[N_IMG];
    const int b = blockIdx.x;
    const int head = b / N_IMG;
    const int r    = b - head * N_IMG;
    switch (head) {
        case 0:  row_max<200, 27, 0>   (in, delta_u, lds, r, 0); break;
        case 1:  row_max<150, 36, 729> (in, delta_u, lds, r, 1); break;
        case 2:  row_max<120, 45, 2025>(in, delta_u, lds, r, 2); break;
        default: row_max<100, 54, 4050>(in, delta_u, lds, r, 3); break;
    }
}

// ---------------------------------------------------------------------------
// K1b: delta -> {scale, recip} with the locked arithmetic.
// ---------------------------------------------------------------------------
__global__ void k1b_scales(const unsigned* __restrict__ delta_u,
                           float2* __restrict__ scales) {
    const int t = blockIdx.x * 256 + threadIdx.x;
    if (t < NTILE) {
        const float delta = __uint_as_float(delta_u[t]);
        const float scale = __fmul_rn(delta, RCP15);
        const float safe  = (scale == 0.0f) ? 1.0f : scale;
        const float recip = __fdiv_rn(1.0f, safe);
        scales[t] = (float2){scale, recip};
    }
}

// ---------------------------------------------------------------------------
// K2: linear float4 sweep (reversed order for L3 reuse of K1's tail).
// Validated bit-exact in r11 -- unchanged.
// ---------------------------------------------------------------------------
template <int BW, int NB, int BASE>
__device__ __forceinline__ void quant_f4(const float* __restrict__ hin,
                                         float* __restrict__ hout,
                                         const float2* __restrict__ scales,
                                         unsigned e, unsigned r, unsigned c) {
    f32x4 v = *(const f32x4*)(hin + e);
    if (r < N_TEXT) { *(f32x4*)(hout + e) = v; return; }          // text rows
    const unsigned bi = (r - N_TEXT) / BW;
    if (c == 5624u) {                                              // row wrap
        const float2 sr = scales[BASE + bi * NB + (NB - 1)];
        v.x = fq1(v.x, sr.y, sr.x);
        v.y = fq1(v.y, sr.y, sr.x);
        *(f32x4*)(hout + e) = v; return;
    }
    if (c + 3u < N_TEXT) { *(f32x4*)(hout + e) = v; return; }      // c<=222
    if (c == 224u) {                                               // text|image
        const float2 sr = scales[BASE + bi * NB];
        v.z = fq1(v.z, sr.y, sr.x);
        v.w = fq1(v.w, sr.y, sr.x);
        *(f32x4*)(hout + e) = v; return;
    }
    const unsigned ic  = c - N_TEXT;
    const unsigned bj0 = ic / BW;
    const unsigned bj3 = (ic + 3u) / BW;
    const float2 s0 = scales[BASE + bi * NB + bj0];
    if (bj0 == bj3) {
        v.x = fq1(v.x, s0.y, s0.x);
        v.y = fq1(v.y, s0.y, s0.x);
        v.z = fq1(v.z, s0.y, s0.x);
        v.w = fq1(v.w, s0.y, s0.x);
    } else {                                                       // tile edge
        const float2 s1 = scales[BASE + bi * NB + bj3];
        const unsigned mm = bj3 * BW - ic;
        const float2 sy = (1u < mm) ? s0 : s1;
        const float2 sz = (2u < mm) ? s0 : s1;
        v.x = fq1(v.x, s0.y, s0.x);
        v.y = fq1(v.y, sy.y, sy.x);
        v.z = fq1(v.z, sz.y, sz.x);
        v.w = fq1(v.w, s1.y, s1.x);
    }
    *(f32x4*)(hout + e) = v;
}

__global__ __launch_bounds__(256)
void k2_quant(const float* __restrict__ in, float* __restrict__ out,
              const float2* __restrict__ scales) {
    const unsigned i = blockIdx.x * 256u + threadIdx.x;
    if (i >= TOTAL_F4) return;
    const unsigned fi   = TOTAL_F4 - 1u - i;   // reversed: L3 reuse of K1 tail
    const unsigned head = fi / HEAD_F4;
    const unsigned e    = (fi - head * HEAD_F4) * 4u;
    const unsigned r    = e / 5626u;
    const unsigned c    = e - r * 5626u;
    const float* hin  = in  + (size_t)head * HEAD_STRIDE;
    float*       hout = out + (size_t)head * HEAD_STRIDE;
    switch (head) {
        case 0:  quant_f4<200, 27, 0>   (hin, hout, scales, e, r, c); break;
        case 1:  quant_f4<150, 36, 729> (hin, hout, scales, e, r, c); break;
        case 2:  quant_f4<120, 45, 2025>(hin, hout, scales, e, r, c); break;
        default: quant_f4<100, 54, 4050>(hin, hout, scales, e, r, c); break;
    }
}

extern "C" void kernel_launch(void* const* d_in, const int* in_sizes, int n_in,
                              void* d_out, int out_size, void* d_ws, size_t ws_size,
                              hipStream_t stream) {
    const float* x  = (const float*)d_in[0];
    float* out      = (float*)d_out;
    unsigned* delta_u = (unsigned*)d_ws;                       // 6966 u32
    float2*   scales  = (float2*)((char*)d_ws + 32768);        // 6966 float2

    k0_init  <<<28, 256, 0, stream>>>(delta_u);
    k1_rowmax<<<4 * N_IMG, 256, 0, stream>>>(x, delta_u);
    k1b_scales<<<28, 256, 0, stream>>>(delta_u, scales);
    const unsigned g2 = (TOTAL_F4 + 255u) / 256u;              // 123641
    k2_quant <<<g2, 256, 0, stream>>>(x, out, scales);
}

// Round 13
// 287.166 us; speedup vs baseline: 1.5821x; 1.5821x over previous
//
#include <hip/hip_runtime.h>
#include <cfloat>
#include <math.h>

// Problem constants
#define N_TEXT  226
#define N_IMG   5400
#define N_TOKEN 5626
#define HEAD_STRIDE 31651876u   // N_TOKEN*N_TOKEN
#define HEAD_F4     7912969u    // HEAD_STRIDE/4
#define TOTAL_F4    31651876u   // 4 heads * HEAD_F4
#define NTILE 6966              // 27^2+36^2+45^2+54^2

// f32(1/15): XLA rewrites divide-by-constant into multiply-by-reciprocal.
#define RCP15 0x1.111112p-4f

typedef float f32x4 __attribute__((ext_vector_type(4)));
typedef float f32x2 __attribute__((ext_vector_type(2)));

// Locked bit-exact arithmetic (verified r9/r11, absmax=0):
//   scale = fl32(delta*fl32(1/15)); safe = scale==0?1:scale;
//   recip = fl32(1/safe); q = clip(roundeven(fl32(x*recip)),0,15);
//   out = fl32(q*scale).
__device__ __forceinline__ float fq1(float x, float recip, float scale) {
    float q = rintf(__fmul_rn(x, recip));
    q = fminf(fmaxf(q, 0.0f), 15.0f);
    return __fmul_rn(q, scale);
}

// ---------------------------------------------------------------------------
// K0: zero the delta LUT (ws is poisoned 0xAA; must re-init every launch).
// ---------------------------------------------------------------------------
__global__ void k0_init(unsigned* __restrict__ delta_u) {
    const int t = blockIdx.x * 256 + threadIdx.x;
    if (t < NTILE) delta_u[t] = 0u;
}

// ---------------------------------------------------------------------------
// K1: column-banded register max. Block = (head, strip s = tile row, band b =
// 1024 cols). Thread owns 4 fixed columns; accumulates max over the strip's
// BW rows in 2 regs (A/B for tile straddle). Per row the block reads 4KB
// contiguous. End: 16-slot LDS bin -> <=12 global atomicMax per block.
// atomicMax on float-as-uint is exact for non-negative floats (r12-verified).
// ---------------------------------------------------------------------------
template <int BW, int NB, int BASE>
__device__ __forceinline__ void band_max(const float* __restrict__ in,
                                         unsigned* __restrict__ delta_u,
                                         int s, int b, int head) {
    const int t   = threadIdx.x;
    const int ic0 = b * 1024 + (t << 2);            // image col of elem 0
    const int icEnd = min((b + 1) * 1024, N_IMG);
    const bool act  = (ic0 < icEnd);                // 5400%4==0: full quads

    int bjA = 0, bjB = 0, kSplit = 4;
    if (act) {
        bjA = ic0 / BW;
        bjB = (ic0 + 3) / BW;
        kSplit = (bjB > bjA) ? (bjB * BW - ic0) : 4;
    }

    float accA = 0.0f, accB = 0.0f;                 // inputs are >= 0
    if (act) {
        const size_t rb0 = (size_t)head * HEAD_STRIDE
                         + (size_t)(N_TEXT + s * BW) * N_TOKEN
                         + N_TEXT + ic0;
        #pragma unroll 4
        for (int r = 0; r < BW; ++r) {
            const float* p = in + rb0 + (size_t)r * N_TOKEN;
            f32x2 v0 = *(const f32x2*)(p);          // cols even -> 8B aligned
            f32x2 v1 = *(const f32x2*)(p + 2);
            accA = fmaxf(accA, v0.x);               // k=0 always in A
            if (kSplit > 1) accA = fmaxf(accA, v0.y); else accB = fmaxf(accB, v0.y);
            if (kSplit > 2) accA = fmaxf(accA, v1.x); else accB = fmaxf(accB, v1.x);
            if (kSplit > 3) accA = fmaxf(accA, v1.y); else accB = fmaxf(accB, v1.y);
        }
    }

    __shared__ unsigned slots[16];                  // band spans <= 12 bjs
    const int bjBase = (b * 1024) / BW;
    if (t < 16) slots[t] = 0u;
    __syncthreads();
    if (act) {
        atomicMax(&slots[bjA - bjBase], __float_as_uint(accA));
        if (bjB > bjA) atomicMax(&slots[bjB - bjBase], __float_as_uint(accB));
    }
    __syncthreads();
    if (t < 16) {
        const int bj = bjBase + t;
        const unsigned v = slots[t];
        if (bj < NB && v != 0u)
            atomicMax(&delta_u[BASE + s * NB + bj], v);
    }
}

__global__ __launch_bounds__(256)
void k1_bandmax(const float* __restrict__ in, unsigned* __restrict__ delta_u) {
    const int b = blockIdx.x;                       // 972 blocks total
    if (b < 162)      { const int l = b;       band_max<200, 27, 0>   (in, delta_u, l / 6, l % 6, 0); }
    else if (b < 378) { const int l = b - 162; band_max<150, 36, 729> (in, delta_u, l / 6, l % 6, 1); }
    else if (b < 648) { const int l = b - 378; band_max<120, 45, 2025>(in, delta_u, l / 6, l % 6, 2); }
    else              { const int l = b - 648; band_max<100, 54, 4050>(in, delta_u, l / 6, l % 6, 3); }
}

// ---------------------------------------------------------------------------
// K1b: delta -> {scale, recip} with the locked arithmetic.
// ---------------------------------------------------------------------------
__global__ void k1b_scales(const unsigned* __restrict__ delta_u,
                           float2* __restrict__ scales) {
    const int t = blockIdx.x * 256 + threadIdx.x;
    if (t < NTILE) {
        const float delta = __uint_as_float(delta_u[t]);
        const float scale = __fmul_rn(delta, RCP15);
        const float safe  = (scale == 0.0f) ? 1.0f : scale;
        const float recip = __fdiv_rn(1.0f, safe);
        scales[t] = (float2){scale, recip};
    }
}

// ---------------------------------------------------------------------------
// K2: linear float4 sweep (reversed order for L3 reuse of K1's tail).
// Validated bit-exact in r11 -- unchanged.
// ---------------------------------------------------------------------------
template <int BW, int NB, int BASE>
__device__ __forceinline__ void quant_f4(const float* __restrict__ hin,
                                         float* __restrict__ hout,
                                         const float2* __restrict__ scales,
                                         unsigned e, unsigned r, unsigned c) {
    f32x4 v = *(const f32x4*)(hin + e);
    if (r < N_TEXT) { *(f32x4*)(hout + e) = v; return; }          // text rows
    const unsigned bi = (r - N_TEXT) / BW;
    if (c == 5624u) {                                              // row wrap
        const float2 sr = scales[BASE + bi * NB + (NB - 1)];
        v.x = fq1(v.x, sr.y, sr.x);
        v.y = fq1(v.y, sr.y, sr.x);
        *(f32x4*)(hout + e) = v; return;
    }
    if (c + 3u < N_TEXT) { *(f32x4*)(hout + e) = v; return; }      // c<=222
    if (c == 224u) {                                               // text|image
        const float2 sr = scales[BASE + bi * NB];
        v.z = fq1(v.z, sr.y, sr.x);
        v.w = fq1(v.w, sr.y, sr.x);
        *(f32x4*)(hout + e) = v; return;
    }
    const unsigned ic  = c - N_TEXT;
    const unsigned bj0 = ic / BW;
    const unsigned bj3 = (ic + 3u) / BW;
    const float2 s0 = scales[BASE + bi * NB + bj0];
    if (bj0 == bj3) {
        v.x = fq1(v.x, s0.y, s0.x);
        v.y = fq1(v.y, s0.y, s0.x);
        v.z = fq1(v.z, s0.y, s0.x);
        v.w = fq1(v.w, s0.y, s0.x);
    } else {                                                       // tile edge
        const float2 s1 = scales[BASE + bi * NB + bj3];
        const unsigned mm = bj3 * BW - ic;
        const float2 sy = (1u < mm) ? s0 : s1;
        const float2 sz = (2u < mm) ? s0 : s1;
        v.x = fq1(v.x, s0.y, s0.x);
        v.y = fq1(v.y, sy.y, sy.x);
        v.z = fq1(v.z, sz.y, sz.x);
        v.w = fq1(v.w, s1.y, s1.x);
    }
    *(f32x4*)(hout + e) = v;
}

__global__ __launch_bounds__(256)
void k2_quant(const float* __restrict__ in, float* __restrict__ out,
              const float2* __restrict__ scales) {
    const unsigned i = blockIdx.x * 256u + threadIdx.x;
    if (i >= TOTAL_F4) return;
    const unsigned fi   = TOTAL_F4 - 1u - i;   // reversed: L3 reuse of K1 tail
    const unsigned head = fi / HEAD_F4;
    const unsigned e    = (fi - head * HEAD_F4) * 4u;
    const unsigned r    = e / 5626u;
    const unsigned c    = e - r * 5626u;
    const float* hin  = in  + (size_t)head * HEAD_STRIDE;
    float*       hout = out + (size_t)head * HEAD_STRIDE;
    switch (head) {
        case 0:  quant_f4<200, 27, 0>   (hin, hout, scales, e, r, c); break;
        case 1:  quant_f4<150, 36, 729> (hin, hout, scales, e, r, c); break;
        case 2:  quant_f4<120, 45, 2025>(hin, hout, scales, e, r, c); break;
        default: quant_f4<100, 54, 4050>(hin, hout, scales, e, r, c); break;
    }
}

extern "C" void kernel_launch(void* const* d_in, const int* in_sizes, int n_in,
                              void* d_out, int out_size, void* d_ws, size_t ws_size,
                              hipStream_t stream) {
    const float* x  = (const float*)d_in[0];
    float* out      = (float*)d_out;
    unsigned* delta_u = (unsigned*)d_ws;                       // 6966 u32
    float2*   scales  = (float2*)((char*)d_ws + 32768);        // 6966 float2

    k0_init   <<<28, 256, 0, stream>>>(delta_u);
    k1_bandmax<<<972, 256, 0, stream>>>(x, delta_u);
    k1b_scales<<<28, 256, 0, stream>>>(delta_u, scales);
    const unsigned g2 = (TOTAL_F4 + 255u) / 256u;              // 123641
    k2_quant  <<<g2, 256, 0, stream>>>(x, out, scales);
}

// Round 14
// 259.678 us; speedup vs baseline: 1.7496x; 1.1059x over previous
//
#include <hip/hip_runtime.h>
#include <cfloat>
#include <math.h>

// Problem constants
#define N_TEXT  226
#define N_IMG   5400
#define N_TOKEN 5626
#define HEAD_STRIDE 31651876u   // N_TOKEN*N_TOKEN
#define HEAD_F4     7912969u    // HEAD_STRIDE/4
#define TOTAL_F4    31651876u   // 4 heads * HEAD_F4
#define TOTAL_ELEMS 126607504u  // 4 * HEAD_STRIDE
#define NTILE 6966              // 27^2+36^2+45^2+54^2

// f32(1/15): XLA rewrites divide-by-constant into multiply-by-reciprocal.
#define RCP15 0x1.111112p-4f

typedef float f32x4 __attribute__((ext_vector_type(4)));
typedef float f32x2 __attribute__((ext_vector_type(2)));

// Locked bit-exact arithmetic (verified r9/r11, absmax=0):
//   scale = fl32(delta*fl32(1/15)); safe = scale==0?1:scale;
//   recip = fl32(1/safe); q = clip(roundeven(fl32(x*recip)),0,15);
//   out = fl32(q*scale).
__device__ __forceinline__ float fq1(float x, float recip, float scale) {
    float q = rintf(__fmul_rn(x, recip));
    q = fminf(fmaxf(q, 0.0f), 15.0f);
    return __fmul_rn(q, scale);
}

// ---------------------------------------------------------------------------
// K1: per-tile block max via flat ALIGNED-f4 sweep with edge masking.
// Each row has NQ = BW/4+1 aligned f4 slots starting at (rowbase & ~3);
// out-of-tile lanes masked to 0 (exact: inputs >= 0). No atomics; block owns
// its tile and writes {scale, recip} directly (folds old k1b + k0 away).
// ---------------------------------------------------------------------------
template <int BW, int NB, int BASE>
__device__ __forceinline__ void tile_max_v2(const float* __restrict__ in,
                                            float2* __restrict__ scales,
                                            int local, int head) {
    constexpr int NQ   = BW / 4 + 1;     // 51 / 38 / 31 / 26 (uniform per row)
    constexpr int TOTQ = BW * NQ;

    const int bi = local / NB;
    const int bj = local - bi * NB;
    const unsigned base = (unsigned)head * HEAD_STRIDE
                        + (unsigned)(N_TEXT + bi * BW) * N_TOKEN
                        + (unsigned)(N_TEXT + bj * BW);
    const int tid = threadIdx.x;

    float m = 0.0f;                       // inputs are >= 0
    for (int i = tid; i < TOTQ; i += 256) {
        const int r = i / NQ;             // compile-time divisor
        const int k = i - r * NQ;
        const unsigned rowbase = base + (unsigned)r * N_TOKEN;
        const int s = (int)(rowbase & 3u);            // 0 or 2
        const unsigned a0 = rowbase - s + (unsigned)(k << 2);
        if (a0 + 4u <= TOTAL_ELEMS) {                 // 8B tail guard
            f32x4 v = *(const f32x4*)(in + a0);
            const int c0 = (k << 2) - s;              // tile-rel col of v.x
            m = fmaxf(m, (c0 >= 0 && c0 < BW)     ? v.x : 0.0f);
            m = fmaxf(m, (c0 + 1 >= 0 && c0 + 1 < BW) ? v.y : 0.0f);
            m = fmaxf(m, (c0 + 2 < BW)            ? v.z : 0.0f);  // c0+2>=0 always
            m = fmaxf(m, (c0 + 3 < BW)            ? v.w : 0.0f);
        }
    }
    #pragma unroll
    for (int o = 32; o > 0; o >>= 1)
        m = fmaxf(m, __shfl_xor(m, o));
    __shared__ float sm[4];
    if ((tid & 63) == 0) sm[tid >> 6] = m;
    __syncthreads();
    if (tid == 0) {
        const float delta = fmaxf(fmaxf(sm[0], sm[1]), fmaxf(sm[2], sm[3]));
        const float scale = __fmul_rn(delta, RCP15);
        const float safe  = (scale == 0.0f) ? 1.0f : scale;
        const float recip = __fdiv_rn(1.0f, safe);
        scales[BASE + local] = (float2){scale, recip};
    }
}

__global__ __launch_bounds__(256)
void k1_max(const float* __restrict__ in, float2* __restrict__ scales) {
    const int b = blockIdx.x;
    if (b < 729)        tile_max_v2<200, 27, 0>   (in, scales, b,        0);
    else if (b < 2025)  tile_max_v2<150, 36, 729> (in, scales, b - 729,  1);
    else if (b < 4050)  tile_max_v2<120, 45, 2025>(in, scales, b - 2025, 2);
    else                tile_max_v2<100, 54, 4050>(in, scales, b - 4050, 3);
}

// ---------------------------------------------------------------------------
// K2: linear float4 sweep (reversed order for L3 reuse of K1's tail).
// Validated bit-exact in r11 -- unchanged.
// ---------------------------------------------------------------------------
template <int BW, int NB, int BASE>
__device__ __forceinline__ void quant_f4(const float* __restrict__ hin,
                                         float* __restrict__ hout,
                                         const float2* __restrict__ scales,
                                         unsigned e, unsigned r, unsigned c) {
    f32x4 v = *(const f32x4*)(hin + e);
    if (r < N_TEXT) { *(f32x4*)(hout + e) = v; return; }          // text rows
    const unsigned bi = (r - N_TEXT) / BW;
    if (c == 5624u) {                                              // row wrap
        const float2 sr = scales[BASE + bi * NB + (NB - 1)];
        v.x = fq1(v.x, sr.y, sr.x);
        v.y = fq1(v.y, sr.y, sr.x);
        *(f32x4*)(hout + e) = v; return;
    }
    if (c + 3u < N_TEXT) { *(f32x4*)(hout + e) = v; return; }      // c<=222
    if (c == 224u) {                                               // text|image
        const float2 sr = scales[BASE + bi * NB];
        v.z = fq1(v.z, sr.y, sr.x);
        v.w = fq1(v.w, sr.y, sr.x);
        *(f32x4*)(hout + e) = v; return;
    }
    const unsigned ic  = c - N_TEXT;
    const unsigned bj0 = ic / BW;
    const unsigned bj3 = (ic + 3u) / BW;
    const float2 s0 = scales[BASE + bi * NB + bj0];
    if (bj0 == bj3) {
        v.x = fq1(v.x, s0.y, s0.x);
        v.y = fq1(v.y, s0.y, s0.x);
        v.z = fq1(v.z, s0.y, s0.x);
        v.w = fq1(v.w, s0.y, s0.x);
    } else {                                                       // tile edge
        const float2 s1 = scales[BASE + bi * NB + bj3];
        const unsigned mm = bj3 * BW - ic;
        const float2 sy = (1u < mm) ? s0 : s1;
        const float2 sz = (2u < mm) ? s0 : s1;
        v.x = fq1(v.x, s0.y, s0.x);
        v.y = fq1(v.y, sy.y, sy.x);
        v.z = fq1(v.z, sz.y, sz.x);
        v.w = fq1(v.w, s1.y, s1.x);
    }
    *(f32x4*)(hout + e) = v;
}

__global__ __launch_bounds__(256)
void k2_quant(const float* __restrict__ in, float* __restrict__ out,
              const float2* __restrict__ scales) {
    const unsigned i = blockIdx.x * 256u + threadIdx.x;
    if (i >= TOTAL_F4) return;
    const unsigned fi   = TOTAL_F4 - 1u - i;   // reversed: L3 reuse of K1 tail
    const unsigned head = fi / HEAD_F4;
    const unsigned e    = (fi - head * HEAD_F4) * 4u;
    const unsigned r    = e / 5626u;
    const unsigned c    = e - r * 5626u;
    const float* hin  = in  + (size_t)head * HEAD_STRIDE;
    float*       hout = out + (size_t)head * HEAD_STRIDE;
    switch (head) {
        case 0:  quant_f4<200, 27, 0>   (hin, hout, scales, e, r, c); break;
        case 1:  quant_f4<150, 36, 729> (hin, hout, scales, e, r, c); break;
        case 2:  quant_f4<120, 45, 2025>(hin, hout, scales, e, r, c); break;
        default: quant_f4<100, 54, 4050>(hin, hout, scales, e, r, c); break;
    }
}

extern "C" void kernel_launch(void* const* d_in, const int* in_sizes, int n_in,
                              void* d_out, int out_size, void* d_ws, size_t ws_size,
                              hipStream_t stream) {
    const float* x = (const float*)d_in[0];
    float* out     = (float*)d_out;
    float2* scales = (float2*)d_ws;                            // 6966 float2

    k1_max  <<<NTILE, 256, 0, stream>>>(x, scales);
    const unsigned g2 = (TOTAL_F4 + 255u) / 256u;              // 123641
    k2_quant<<<g2, 256, 0, stream>>>(x, out, scales);
}